// Round 9
// baseline (645.728 us; speedup 1.0000x reference)
//
#include <hip/hip_runtime.h>
#include <hip/hip_cooperative_groups.h>
#include <math.h>

namespace cg = cooperative_groups;

#define LNUM 3
#define ENUM 8
#define BSZ 256
#define NSZ 1024
#define DSZ 512
#define SSZ 128

typedef float f32x4 __attribute__((ext_vector_type(4)));
typedef float f32x2 __attribute__((ext_vector_type(2)));

// ---- 32x64 C-tile GEMM core: returns this thread's f32x2 accumulator ----
// Ap = A + m0*lda (rows 0..31 used), Bp = B + n0 (column offset baked in).
// Thread t: m = t>>5 (row), np = t&31 (col pair n0 + 2*np).
__device__ __forceinline__ f32x2 gemm_tile(
    float* __restrict__ sm, const float* __restrict__ Ap, int lda,
    const float* __restrict__ Bp, int ldb, int K, int t)
{
    float* As = sm;          // [32][66] padded
    float* Bs = sm + 2112;   // [64][64]
    const int m  = t >> 5, np = t & 31;
    const int ar = t >> 5, ak = (t & 31) * 2;
    const int br = t >> 4, bq4 = (t & 15) * 4;
    f32x2 acc = {0.f, 0.f};
    for (int ks = 0; ks < K; ks += 64) {
        __syncthreads();
        *(f32x2*)&As[ar * 66 + ak] = *(const f32x2*)(Ap + (size_t)ar * lda + ks + ak);
        *(f32x4*)&Bs[br * 64 + bq4] = *(const f32x4*)(Bp + (size_t)(ks + br) * ldb + bq4);
        __syncthreads();
        #pragma unroll
        for (int k = 0; k < 64; ++k) {
            const float a = As[m * 66 + k];
            const f32x2 b2 = *(const f32x2*)&Bs[k * 64 + np * 2];
            acc.x = fmaf(a, b2.x, acc.x);
            acc.y = fmaf(a, b2.y, acc.y);
        }
    }
    return acc;
}

__global__ __launch_bounds__(1024, 1) void coop_kernel(
    const float* __restrict__ token, const float* __restrict__ node_emb,
    const float* __restrict__ states, const float* __restrict__ Wg,
    const float* __restrict__ bg, const float* __restrict__ A,
    const float* __restrict__ Bin, const float* __restrict__ Cout,
    const float* __restrict__ Dsk, const float* __restrict__ Wq,
    const float* __restrict__ bq,
    float* __restrict__ out_logits, float* __restrict__ out_states,
    float* __restrict__ out_loss,
    float* __restrict__ hbuf, float* __restrict__ g1raw,
    float* __restrict__ sng, float* __restrict__ gates,
    float* __restrict__ accp, float* __restrict__ qbuf)
{
    cg::grid_group grid = cg::this_grid();
    const int bid = blockIdx.x;
    const int t = threadIdx.x;
    __shared__ __align__(16) float sm[10240];   // 40 KB scratch, reused per phase

    for (int l = 0; l < LNUM; ++l) {
        const float* hsrc  = (l == 0) ? token : hbuf;
        const float* Wg_l  = Wg + (size_t)l * DSZ * ENUM;
        const float* bg_l  = bg + l * ENUM;
        const float* A_l   = A + (size_t)l * ENUM * SSZ;
        const float* Bin_l = Bin + (size_t)l * ENUM * DSZ * SSZ;
        const float* Cou_l = Cout + (size_t)l * ENUM * SSZ * DSZ;
        const float* Dsk_l = Dsk + (size_t)l * ENUM * DSZ;
        const float* st_l  = states + (size_t)l * ENUM * BSZ * SSZ;
        float* os_l        = out_states + (size_t)l * ENUM * BSZ * SSZ;

        // ======== P_A: dense G1 = h @ Bin_all (blocks 0..127) || gating (128..159) ========
        if (bid < 128) {
            const int mt = bid >> 4, nt = bid & 15;
            const int m0 = mt * 32, n0 = nt * 64;
            const f32x2 acc = gemm_tile(sm, hsrc + (size_t)m0 * DSZ, DSZ,
                                        Bin_l + (size_t)(nt >> 1) * DSZ * SSZ + (nt & 1) * 64,
                                        SSZ, DSZ, t);
            const int m = t >> 5, np = t & 31;
            *(f32x2*)(g1raw + (size_t)(m0 + m) * 1024 + n0 + np * 2) = acc;
        } else if (bid < 160) {
            const int b0 = (bid - 128) * 8;
            float* wg_s = sm;          // 4096 floats
            float* h_s  = sm + 4096;   // 4096
            float* lgp  = sm + 8192;   // 1024
            float* lg   = sm + 9216;   // 64
            float* ps   = sm + 9280;   // 64
            float* sl   = sm + 9344;   // 64
            ((f32x4*)wg_s)[t] = ((const f32x4*)Wg_l)[t];
            ((f32x4*)h_s)[t]  = ((const f32x4*)(hsrc + (size_t)b0 * DSZ))[t];
            __syncthreads();
            {
                const int tok = t >> 7, e = (t >> 4) & 7, kq = t & 15;
                float p = 0.f;
                #pragma unroll
                for (int j = 0; j < 32; ++j) {
                    const int d = kq + j * 16;
                    p = fmaf(h_s[tok * DSZ + d], wg_s[d * ENUM + e], p);
                }
                lgp[t] = p;
            }
            __syncthreads();
            if (t < 64) {
                const int tok = t >> 3, e = t & 7;
                float s = bg_l[e];
                #pragma unroll
                for (int kq = 0; kq < 16; ++kq) s += lgp[tok * 128 + e * 16 + kq];
                lg[tok * 8 + e] = s;
            }
            __syncthreads();
            if (t < 8) {
                float probs[ENUM];
                float mx = lg[t * 8];
                for (int e = 1; e < ENUM; ++e) mx = fmaxf(mx, lg[t * 8 + e]);
                float ss = 0.f;
                for (int e = 0; e < ENUM; ++e) { probs[e] = expf(lg[t * 8 + e] - mx); ss += probs[e]; }
                const float sinv = 1.f / ss;
                for (int e = 0; e < ENUM; ++e) probs[e] *= sinv;
                int i0 = 0;
                for (int e = 1; e < ENUM; ++e) if (probs[e] > probs[i0]) i0 = e;
                int i1 = -1;
                for (int e = 0; e < ENUM; ++e) {
                    if (e == i0) continue;
                    if (i1 < 0 || probs[e] > probs[i1]) i1 = e;
                }
                const float gs = 1.f / (probs[i0] + probs[i1]);
                for (int e = 0; e < ENUM; ++e) {
                    const int selv = (e == i0 || e == i1) ? 1 : 0;
                    gates[(b0 + t) * ENUM + e] = selv ? probs[e] * gs : 0.f;
                    ps[t * 8 + e] = probs[e];
                    sl[t * 8 + e] = (float)selv;
                }
            }
            __syncthreads();
            if (t < 16) {   // per-block partials (no atomics, deterministic)
                const int e = t & 7;
                float s = 0.f;
                if (t < 8) {
                    for (int tok = 0; tok < 8; ++tok) s += ps[tok * 8 + e];
                    accp[((l * 32) + (bid - 128)) * 16 + e] = s;
                } else {
                    for (int tok = 0; tok < 8; ++tok) s += sl[tok * 8 + e];
                    accp[((l * 32) + (bid - 128)) * 16 + 8 + e] = s;
                }
            }
        }
        grid.sync();

        // ======== P_B: combine -> out_states + gated s_new (blocks 0..63) ========
        if (bid < 64) {
            const int gid = bid * 1024 + t;        // quad id, 65536 total
            const int b = gid >> 8, nq = gid & 255;
            const int e = nq >> 5, sq = (nq & 31) * 4;
            const f32x4 g1q = *(const f32x4*)(g1raw + (size_t)b * 1024 + nq * 4);
            const f32x4 stq = *(const f32x4*)(st_l + (size_t)e * BSZ * SSZ + b * SSZ + sq);
            const f32x4 aq  = *(const f32x4*)(A_l + e * SSZ + sq);
            f32x4 dec;
            dec.x = 1.f / (1.f + expf(-aq.x));
            dec.y = 1.f / (1.f + expf(-aq.y));
            dec.z = 1.f / (1.f + expf(-aq.z));
            dec.w = 1.f / (1.f + expf(-aq.w));
            const f32x4 snew = dec * stq + g1q;
            const float g = gates[b * ENUM + e];
            *(f32x4*)(os_l + (size_t)e * BSZ * SSZ + b * SSZ + sq) = (g > 0.f) ? snew : stq;
            *(f32x4*)(sng + (size_t)b * 1024 + nq * 4) = snew * g;
        }
        grid.sync();

        // ======== P_C: dense G2 = sng @ Cout_all + h update (blocks 0..63) ========
        if (bid < 64) {
            const int mt = bid >> 3, nt = bid & 7;
            const int m0 = mt * 32, n0 = nt * 64;
            const f32x2 acc = gemm_tile(sm, sng + (size_t)m0 * 1024, 1024,
                                        Cou_l + n0, DSZ, 1024, t);
            const int m = t >> 5, np = t & 31;
            const int b = m0 + m, d = n0 + np * 2;
            float w0 = 0.f, w1 = 0.f;
            #pragma unroll
            for (int e = 0; e < ENUM; ++e) {
                const float g = gates[b * ENUM + e];
                w0 = fmaf(g, Dsk_l[e * DSZ + d], w0);
                w1 = fmaf(g, Dsk_l[e * DSZ + d + 1], w1);
            }
            const f32x2 hold = *(const f32x2*)(hsrc + (size_t)b * DSZ + d);
            f32x2 hn;
            hn.x = hold.x + acc.x + hold.x * w0;
            hn.y = hold.y + acc.y + hold.y * w1;
            *(f32x2*)(hbuf + (size_t)b * DSZ + d) = hn;
        }
        grid.sync();
    }

    // ======== P_q: q = h3 @ Wq + bq (blocks 0..63) + lb_loss (block 64) ========
    if (bid < 64) {
        const int mt = bid >> 3, nt = bid & 7;
        const int m0 = mt * 32, n0 = nt * 64;
        const f32x2 acc = gemm_tile(sm, hbuf + (size_t)m0 * DSZ, DSZ,
                                    Wq + n0, DSZ, DSZ, t);
        const int m = t >> 5, np = t & 31;
        const int d = n0 + np * 2;
        f32x2 qv;
        qv.x = acc.x + bq[d];
        qv.y = acc.y + bq[d + 1];
        *(f32x2*)(qbuf + (size_t)(m0 + m) * DSZ + d) = qv;
    } else if (bid == 64) {
        float* red = sm;
        if (t < 24) {
            const int l = t >> 3, e = t & 7;
            float mp = 0.f, ms = 0.f;
            for (int gb = 0; gb < 32; ++gb) {
                mp += accp[(l * 32 + gb) * 16 + e];
                ms += accp[(l * 32 + gb) * 16 + 8 + e];
            }
            red[t] = (float)ENUM * (mp * (1.f / BSZ)) * (ms * (1.f / BSZ));
        }
        __syncthreads();
        if (t == 0) {
            float lb = 0.f;
            for (int i = 0; i < 24; ++i) lb += red[i];
            out_loss[0] = lb;
        }
    }
    grid.sync();

    // ======== P_logits: block b streams node_emb[b] (all 256 blocks) ========
    {
        const int b = bid;
        const int wave = t >> 6, lane = t & 63;
        const f32x4* q4 = (const f32x4*)(qbuf + (size_t)b * DSZ);
        const f32x4 q0 = q4[lane];
        const f32x4 q1 = q4[lane + 64];
        const float scale = 0.04419417382415922f;  // 1/sqrt(512)
        const int n0 = wave * 64;
        for (int i = 0; i < 64; i += 2) {
            const f32x4* r0 = (const f32x4*)(node_emb + ((size_t)b * NSZ + n0 + i) * DSZ);
            const f32x4* r1 = (const f32x4*)(node_emb + ((size_t)b * NSZ + n0 + i + 1) * DSZ);
            const f32x4 a0 = __builtin_nontemporal_load(r0 + lane);
            const f32x4 a1 = __builtin_nontemporal_load(r0 + lane + 64);
            const f32x4 c0 = __builtin_nontemporal_load(r1 + lane);
            const f32x4 c1 = __builtin_nontemporal_load(r1 + lane + 64);
            float d0 = a0.x*q0.x + a0.y*q0.y + a0.z*q0.z + a0.w*q0.w
                     + a1.x*q1.x + a1.y*q1.y + a1.z*q1.z + a1.w*q1.w;
            float d1 = c0.x*q0.x + c0.y*q0.y + c0.z*q0.z + c0.w*q0.w
                     + c1.x*q1.x + c1.y*q1.y + c1.z*q1.z + c1.w*q1.w;
            #pragma unroll
            for (int off = 32; off; off >>= 1) {
                d0 += __shfl_down(d0, off, 64);
                d1 += __shfl_down(d1, off, 64);
            }
            if (lane == 0) {
                out_logits[b * NSZ + n0 + i]     = d0 * scale;
                out_logits[b * NSZ + n0 + i + 1] = d1 * scale;
            }
        }
    }
}

extern "C" void kernel_launch(void* const* d_in, const int* in_sizes, int n_in,
                              void* d_out, int out_size, void* d_ws, size_t ws_size,
                              hipStream_t stream) {
    const float* token    = (const float*)d_in[0];  // B,1,D
    const float* node_emb = (const float*)d_in[1];  // B,N,D
    const float* states   = (const float*)d_in[2];  // L,E,B,DS
    const float* Wg       = (const float*)d_in[3];  // L,D,E
    const float* bg       = (const float*)d_in[4];  // L,E
    const float* A        = (const float*)d_in[5];  // L,E,DS
    const float* Bin      = (const float*)d_in[6];  // L,E,D,DS
    const float* Cout     = (const float*)d_in[7];  // L,E,DS,D
    const float* Dsk      = (const float*)d_in[8];  // L,E,D
    const float* Wq       = (const float*)d_in[9];  // D,D
    const float* bq       = (const float*)d_in[10]; // D

    float* out_logits = (float*)d_out;                                  // B*N
    float* out_states = out_logits + (size_t)BSZ * NSZ;                 // L*E*B*DS
    float* out_loss   = out_states + (size_t)LNUM * ENUM * BSZ * SSZ;   // 1

    // workspace (floats) — every buffer fully written before read each call
    float* hbuf  = (float*)d_ws;            // 131072
    float* g1raw = hbuf + 131072;           // 262144
    float* sng   = g1raw + 262144;          // 262144
    float* qbuf  = sng + 262144;            // 131072
    float* gates = qbuf + 131072;           // 2048
    float* accp  = gates + 2048;            // 1536

    void* args[] = {
        (void*)&token, (void*)&node_emb, (void*)&states, (void*)&Wg, (void*)&bg,
        (void*)&A, (void*)&Bin, (void*)&Cout, (void*)&Dsk, (void*)&Wq, (void*)&bq,
        (void*)&out_logits, (void*)&out_states, (void*)&out_loss,
        (void*)&hbuf, (void*)&g1raw, (void*)&sng, (void*)&gates,
        (void*)&accp, (void*)&qbuf
    };

    (void)hipLaunchCooperativeKernel((const void*)coop_kernel,
                                     dim3(256), dim3(1024), args, 0, stream);
}

// Round 10
// 164.459 us; speedup vs baseline: 3.9264x; 3.9264x over previous
//
#include <hip/hip_runtime.h>
#include <math.h>

#define LNUM 3
#define ENUM 8
#define TOPK 2
#define BSZ 256
#define NSZ 1024
#define DSZ 512
#define SSZ 128   // DS

typedef float f32x4 __attribute__((ext_vector_type(4)));

// ---------------- fused kernel: 3 layers + q ----------------
// grid = BSZ blocks, block = 1024 threads (16 waves). Block b owns token b.
// h lives in LDS across all layers. The two selected experts are processed
// SEQUENTIALLY (all 1024 threads each) so the per-instant weight working set
// per XCD stays ~2 MB (one matrix family) and L2 captures cross-block reuse.
__global__ __launch_bounds__(1024, 2) void fused_kernel(
    const float* __restrict__ token,   // [B][D]
    const float* __restrict__ states,  // [L][E][B][DS]
    const float* __restrict__ Wg,      // [L][D][E]
    const float* __restrict__ bg,      // [L][E]
    const float* __restrict__ A,       // [L][E][DS]
    const float* __restrict__ Bin,     // [L][E][D][DS]
    const float* __restrict__ Cout,    // [L][E][DS][D]
    const float* __restrict__ Dsk,     // [L][E][D]
    const float* __restrict__ Wq,      // [D][D]
    const float* __restrict__ bq,      // [D]
    float* __restrict__ out_states,    // [L][E][B][DS]
    float* __restrict__ acc,           // [L][2][E] (probs, sel) — pre-zeroed
    float* __restrict__ q_out)         // [B][D]
{
    const int b = blockIdx.x;
    const int t = threadIdx.x;
    const int wave = t >> 6;
    const int lane = t & 63;

    __shared__ float h_s[DSZ];
    __shared__ float yacc_s[DSZ];
    __shared__ float snew_s[TOPK][SSZ];
    __shared__ float logit_s[ENUM];
    __shared__ f32x4 part4[1024];      // 16 KB scratch, reused every phase
    float* part = (float*)part4;

    if (t < DSZ) h_s[t] = token[b * DSZ + t];

    for (int l = 0; l < LNUM; ++l) {
        const float* Wg_l  = Wg  + (size_t)l * DSZ * ENUM;
        const float* bg_l  = bg  + (size_t)l * ENUM;
        const float* A_l   = A   + (size_t)l * ENUM * SSZ;
        const float* Bin_l = Bin + (size_t)l * ENUM * DSZ * SSZ;
        const float* Cou_l = Cout+ (size_t)l * ENUM * SSZ * DSZ;
        const float* Dsk_l = Dsk + (size_t)l * ENUM * DSZ;
        const float* st_l  = states     + (size_t)l * ENUM * BSZ * SSZ;
        float*       os_l  = out_states + (size_t)l * ENUM * BSZ * SSZ;

        // stage Wg[l] (16 KB) into part; also fences h_s (l=0 load / l-1 update)
        __syncthreads();
        part4[t] = ((const f32x4*)Wg_l)[t];
        __syncthreads();

        // gating logits: wave w computes expert w
        if (wave < ENUM) {
            float p = 0.f;
            #pragma unroll
            for (int i = 0; i < 8; ++i) {
                const int d = lane + i * 64;
                p = fmaf(h_s[d], part[d * ENUM + wave], p);
            }
            for (int off = 32; off; off >>= 1) p += __shfl_down(p, off, 64);
            if (lane == 0) logit_s[wave] = p + bg_l[wave];
        }
        __syncthreads();

        // softmax + top2, redundantly per thread (identical results)
        float probs[ENUM];
        float mx = logit_s[0];
        for (int e = 1; e < ENUM; ++e) mx = fmaxf(mx, logit_s[e]);
        float ssum = 0.f;
        for (int e = 0; e < ENUM; ++e) { probs[e] = expf(logit_s[e] - mx); ssum += probs[e]; }
        const float sinv = 1.f / ssum;
        for (int e = 0; e < ENUM; ++e) probs[e] *= sinv;

        int i0 = 0;
        for (int e = 1; e < ENUM; ++e) if (probs[e] > probs[i0]) i0 = e;
        int i1 = -1;
        for (int e = 0; e < ENUM; ++e) {
            if (e == i0) continue;
            if (i1 < 0 || probs[e] > probs[i1]) i1 = e;
        }
        float g0 = probs[i0], g1 = probs[i1];
        const float ginv = 1.f / (g0 + g1);
        g0 *= ginv; g1 *= ginv;

        if (t < ENUM) {
            atomicAdd(&acc[(l * 2 + 0) * ENUM + t], probs[t]);
            atomicAdd(&acc[(l * 2 + 1) * ENUM + t], (t == i0 || t == i1) ? 1.0f : 0.0f);
        }

        // ---- s_new: experts sequentially, all 1024 threads each ----
        #pragma unroll
        for (int k = 0; k < TOPK; ++k) {
            const int e = k ? i1 : i0;
            // (part4 free: gating / previous combine done at last barrier)
            {
                const int c  = t >> 5;     // 0..31, K-chunk of 16
                const int sq = t & 31;     // s-quad
                const float* Bp = Bin_l + (size_t)e * DSZ * SSZ + sq * 4;
                const int d0 = c * 16;
                f32x4 acc4 = {0.f, 0.f, 0.f, 0.f};
                #pragma unroll
                for (int d = 0; d < 16; ++d)
                    acc4 += *(const f32x4*)(Bp + (size_t)(d0 + d) * SSZ) * h_s[d0 + d];
                part4[c * 32 + sq] = acc4;
            }
            __syncthreads();
            if (t < SSZ) {
                float sum = 0.f;
                #pragma unroll
                for (int c = 0; c < 32; ++c) sum += part[c * 128 + t];
                const float a = A_l[e * SSZ + t];
                const float decay = 1.f / (1.f + expf(-a));
                snew_s[k][t] = decay * st_l[((size_t)e * BSZ + b) * SSZ + t] + sum;
            }
            __syncthreads();
        }

        // write new_states for all 8 experts (1 elem/thread)
        {
            const int e = t >> 7, s = t & 127;
            float v;
            if (e == i0)      v = snew_s[0][s];
            else if (e == i1) v = snew_s[1][s];
            else              v = st_l[((size_t)e * BSZ + b) * SSZ + s];
            os_l[((size_t)e * BSZ + b) * SSZ + s] = v;
        }

        // ---- y: experts sequentially, all 1024 threads each ----
        #pragma unroll
        for (int k = 0; k < TOPK; ++k) {
            const int e = k ? i1 : i0;
            const float g = k ? g1 : g0;
            {
                const int sc = t >> 7;     // 0..7, S-chunk of 16
                const int dq = t & 127;    // d-quad
                const float* Cp = Cou_l + (size_t)e * SSZ * DSZ + dq * 4;
                const float* sp = snew_s[k];
                const int s0 = sc * 16;
                f32x4 acc4 = {0.f, 0.f, 0.f, 0.f};
                #pragma unroll
                for (int s = 0; s < 16; ++s)
                    acc4 += *(const f32x4*)(Cp + (size_t)(s0 + s) * DSZ) * sp[s0 + s];
                part4[sc * 128 + dq] = acc4;
            }
            __syncthreads();
            if (t < DSZ) {
                float yk = 0.f;
                #pragma unroll
                for (int sc = 0; sc < 8; ++sc) yk += part[sc * 512 + t];
                const float hd = h_s[t];
                yk = g * (yk + hd * Dsk_l[e * DSZ + t]);
                if (k == 0) yacc_s[t] = yk;
                else        h_s[t] = hd + yacc_s[t] + yk;
            }
            __syncthreads();
        }
    }

    // ---- q = h @ Wq + bq ----
    {
        const int chunk = t >> 7;        // 0..7, dd-chunk of 64
        const int dquad = t & 127;
        const int dd0 = chunk * 64;
        f32x4 acc4 = {0.f, 0.f, 0.f, 0.f};
        #pragma unroll 8
        for (int i = 0; i < 64; ++i)
            acc4 += *(const f32x4*)(Wq + (size_t)(dd0 + i) * DSZ + dquad * 4) * h_s[dd0 + i];
        part4[chunk * 128 + dquad] = acc4;
    }
    __syncthreads();
    if (t < DSZ) {
        float qv = bq[t];
        #pragma unroll
        for (int c = 0; c < 8; ++c) qv += part[c * 512 + t];
        q_out[b * DSZ + t] = qv;
    }
}

// ---------------- logits[b,n] = q[b] . node_emb[b,n,:] / sqrt(D) ----------------
// grid = (8, B), block = 256 (4 waves). Each wave: 32 n's, 2-row ILP.
// Block (0,0) thread 0 additionally finishes lb_loss.
__global__ __launch_bounds__(256) void logits_kernel(
    const float* __restrict__ q, const float* __restrict__ node_emb,
    float* __restrict__ logits,
    const float* __restrict__ acc, float* __restrict__ loss_out)
{
    const int b = blockIdx.y;
    const int wave = threadIdx.x >> 6;
    const int lane = threadIdx.x & 63;

    if (blockIdx.x == 0 && blockIdx.y == 0 && threadIdx.x == 0) {
        float lb = 0.f;
        for (int l = 0; l < LNUM; ++l)
            for (int e = 0; e < ENUM; ++e) {
                const float mp = acc[(l * 2 + 0) * ENUM + e] * (1.0f / BSZ);
                const float ms = acc[(l * 2 + 1) * ENUM + e] * (1.0f / BSZ);
                lb += (float)ENUM * mp * ms;
            }
        loss_out[0] = lb;
    }

    const f32x4* q4 = (const f32x4*)(q + b * DSZ);
    const f32x4 q0 = q4[lane];
    const f32x4 q1 = q4[lane + 64];
    const float scale = 0.04419417382415922f;  // 1/sqrt(512)

    const int n0 = blockIdx.x * 128 + wave * 32;
    for (int i = 0; i < 32; i += 2) {
        const f32x4* r0 = (const f32x4*)(node_emb + ((size_t)b * NSZ + n0 + i) * DSZ);
        const f32x4* r1 = (const f32x4*)(node_emb + ((size_t)b * NSZ + n0 + i + 1) * DSZ);
        const f32x4 a0 = __builtin_nontemporal_load(r0 + lane);
        const f32x4 a1 = __builtin_nontemporal_load(r0 + lane + 64);
        const f32x4 c0 = __builtin_nontemporal_load(r1 + lane);
        const f32x4 c1 = __builtin_nontemporal_load(r1 + lane + 64);
        float d0 = a0.x*q0.x + a0.y*q0.y + a0.z*q0.z + a0.w*q0.w
                 + a1.x*q1.x + a1.y*q1.y + a1.z*q1.z + a1.w*q1.w;
        float d1 = c0.x*q0.x + c0.y*q0.y + c0.z*q0.z + c0.w*q0.w
                 + c1.x*q1.x + c1.y*q1.y + c1.z*q1.z + c1.w*q1.w;
        #pragma unroll
        for (int off = 32; off; off >>= 1) {
            d0 += __shfl_down(d0, off, 64);
            d1 += __shfl_down(d1, off, 64);
        }
        if (lane == 0) {
            logits[b * NSZ + n0 + i]     = d0 * scale;
            logits[b * NSZ + n0 + i + 1] = d1 * scale;
        }
    }
}

extern "C" void kernel_launch(void* const* d_in, const int* in_sizes, int n_in,
                              void* d_out, int out_size, void* d_ws, size_t ws_size,
                              hipStream_t stream) {
    const float* token    = (const float*)d_in[0];  // B,1,D
    const float* node_emb = (const float*)d_in[1];  // B,N,D
    const float* states   = (const float*)d_in[2];  // L,E,B,DS
    const float* Wg       = (const float*)d_in[3];  // L,D,E
    const float* bg       = (const float*)d_in[4];  // L,E
    const float* A        = (const float*)d_in[5];  // L,E,DS
    const float* Bin      = (const float*)d_in[6];  // L,E,D,DS
    const float* Cout     = (const float*)d_in[7];  // L,E,DS,D
    const float* Dsk      = (const float*)d_in[8];  // L,E,D
    const float* Wq       = (const float*)d_in[9];  // D,D
    const float* bq       = (const float*)d_in[10]; // D

    float* out_logits = (float*)d_out;                                  // B*N
    float* out_states = out_logits + (size_t)BSZ * NSZ;                 // L*E*B*DS
    float* out_loss   = out_states + (size_t)LNUM * ENUM * BSZ * SSZ;   // 1

    // workspace layout
    float* ws_q   = (float*)d_ws;                            // B*D floats
    float* ws_acc = ws_q + (size_t)BSZ * DSZ;                // 48 floats

    (void)hipMemsetAsync(ws_acc, 0, sizeof(float) * LNUM * 16, stream);

    fused_kernel<<<BSZ, 1024, 0, stream>>>(
        token, states, Wg, bg, A, Bin, Cout, Dsk, Wq, bq,
        out_states, ws_acc, ws_q);

    dim3 lg(NSZ / 128, BSZ);
    logits_kernel<<<lg, 256, 0, stream>>>(ws_q, node_emb, out_logits, ws_acc, out_loss);
}

// Round 11
// 160.109 us; speedup vs baseline: 4.0331x; 1.0272x over previous
//
#include <hip/hip_runtime.h>
#include <math.h>

#define LNUM 3
#define ENUM 8
#define TOPK 2
#define BSZ 256
#define NSZ 1024
#define DSZ 512
#define SSZ 128   // DS

typedef float f32x4 __attribute__((ext_vector_type(4)));

// ---------------- mega kernel: 3 layers + q + logits, block b owns token b ----------------
// grid = BSZ blocks, 1024 threads (16 waves). h lives in LDS across layers;
// q never leaves LDS; each block streams its own node_emb slice for logits.
__global__ __launch_bounds__(1024, 2) void mega_kernel(
    const float* __restrict__ token,   // [B][D]
    const float* __restrict__ node_emb,// [B][N][D]
    const float* __restrict__ states,  // [L][E][B][DS]
    const float* __restrict__ Wg,      // [L][D][E]
    const float* __restrict__ bg,      // [L][E]
    const float* __restrict__ A,       // [L][E][DS]
    const float* __restrict__ Bin,     // [L][E][D][DS]
    const float* __restrict__ Cout,    // [L][E][DS][D]
    const float* __restrict__ Dsk,     // [L][E][D]
    const float* __restrict__ Wq,      // [D][D]
    const float* __restrict__ bq,      // [D]
    float* __restrict__ out_logits,    // [B][N]
    float* __restrict__ out_states,    // [L][E][B][DS]
    float* __restrict__ acc)           // [L][2][E] (probs, sel) — pre-zeroed
{
    const int b = blockIdx.x;
    const int t = threadIdx.x;
    const int wave = t >> 6;
    const int lane = t & 63;

    __shared__ float h_s[DSZ];
    __shared__ float yacc_s[DSZ];      // also q_s in the logits phase
    __shared__ float snew_s[TOPK][SSZ];
    __shared__ float logit_s[ENUM];
    __shared__ f32x4 part4[1024];      // 16 KB scratch, reused every phase
    float* part = (float*)part4;

    if (t < DSZ) h_s[t] = token[b * DSZ + t];

    for (int l = 0; l < LNUM; ++l) {
        const float* Wg_l  = Wg  + (size_t)l * DSZ * ENUM;
        const float* bg_l  = bg  + (size_t)l * ENUM;
        const float* A_l   = A   + (size_t)l * ENUM * SSZ;
        const float* Bin_l = Bin + (size_t)l * ENUM * DSZ * SSZ;
        const float* Cou_l = Cout+ (size_t)l * ENUM * SSZ * DSZ;
        const float* Dsk_l = Dsk + (size_t)l * ENUM * DSZ;
        const float* st_l  = states     + (size_t)l * ENUM * BSZ * SSZ;
        float*       os_l  = out_states + (size_t)l * ENUM * BSZ * SSZ;

        // stage Wg[l] (16 KB) into part; also fences h_s (l=0 load / l-1 update)
        __syncthreads();
        part4[t] = ((const f32x4*)Wg_l)[t];
        __syncthreads();

        // gating logits: wave w computes expert w
        if (wave < ENUM) {
            float p = 0.f;
            #pragma unroll
            for (int i = 0; i < 8; ++i) {
                const int d = lane + i * 64;
                p = fmaf(h_s[d], part[d * ENUM + wave], p);
            }
            for (int off = 32; off; off >>= 1) p += __shfl_down(p, off, 64);
            if (lane == 0) logit_s[wave] = p + bg_l[wave];
        }
        __syncthreads();

        // softmax + top2, redundantly per thread (identical results)
        float probs[ENUM];
        float mx = logit_s[0];
        for (int e = 1; e < ENUM; ++e) mx = fmaxf(mx, logit_s[e]);
        float ssum = 0.f;
        for (int e = 0; e < ENUM; ++e) { probs[e] = expf(logit_s[e] - mx); ssum += probs[e]; }
        const float sinv = 1.f / ssum;
        for (int e = 0; e < ENUM; ++e) probs[e] *= sinv;

        int i0 = 0;
        for (int e = 1; e < ENUM; ++e) if (probs[e] > probs[i0]) i0 = e;
        int i1 = -1;
        for (int e = 0; e < ENUM; ++e) {
            if (e == i0) continue;
            if (i1 < 0 || probs[e] > probs[i1]) i1 = e;
        }
        float g0 = probs[i0], g1 = probs[i1];
        const float ginv = 1.f / (g0 + g1);
        g0 *= ginv; g1 *= ginv;

        if (t < ENUM) {
            atomicAdd(&acc[(l * 2 + 0) * ENUM + t], probs[t]);
            atomicAdd(&acc[(l * 2 + 1) * ENUM + t], (t == i0 || t == i1) ? 1.0f : 0.0f);
        }

        // ---- s_new: experts sequentially, all 1024 threads each ----
        #pragma unroll
        for (int k = 0; k < TOPK; ++k) {
            const int e = k ? i1 : i0;
            {
                const int c  = t >> 5;     // 0..31, K-chunk of 16
                const int sq = t & 31;     // s-quad
                const float* Bp = Bin_l + (size_t)e * DSZ * SSZ + sq * 4;
                const int d0 = c * 16;
                f32x4 acc4 = {0.f, 0.f, 0.f, 0.f};
                #pragma unroll
                for (int d = 0; d < 16; ++d)
                    acc4 += *(const f32x4*)(Bp + (size_t)(d0 + d) * SSZ) * h_s[d0 + d];
                part4[c * 32 + sq] = acc4;
            }
            __syncthreads();
            if (t < SSZ) {
                float sum = 0.f;
                #pragma unroll
                for (int c = 0; c < 32; ++c) sum += part[c * 128 + t];
                const float a = A_l[e * SSZ + t];
                const float decay = 1.f / (1.f + expf(-a));
                snew_s[k][t] = decay * st_l[((size_t)e * BSZ + b) * SSZ + t] + sum;
            }
            __syncthreads();
        }

        // write new_states for all 8 experts (1 elem/thread)
        {
            const int e = t >> 7, s = t & 127;
            float v;
            if (e == i0)      v = snew_s[0][s];
            else if (e == i1) v = snew_s[1][s];
            else              v = st_l[((size_t)e * BSZ + b) * SSZ + s];
            os_l[((size_t)e * BSZ + b) * SSZ + s] = v;
        }

        // ---- y: experts sequentially, all 1024 threads each ----
        #pragma unroll
        for (int k = 0; k < TOPK; ++k) {
            const int e = k ? i1 : i0;
            const float g = k ? g1 : g0;
            {
                const int sc = t >> 7;     // 0..7, S-chunk of 16
                const int dq = t & 127;    // d-quad
                const float* Cp = Cou_l + (size_t)e * SSZ * DSZ + dq * 4;
                const float* sp = snew_s[k];
                const int s0 = sc * 16;
                f32x4 acc4 = {0.f, 0.f, 0.f, 0.f};
                #pragma unroll
                for (int s = 0; s < 16; ++s)
                    acc4 += *(const f32x4*)(Cp + (size_t)(s0 + s) * DSZ) * sp[s0 + s];
                part4[sc * 128 + dq] = acc4;
            }
            __syncthreads();
            if (t < DSZ) {
                float yk = 0.f;
                #pragma unroll
                for (int sc = 0; sc < 8; ++sc) yk += part[sc * 512 + t];
                const float hd = h_s[t];
                yk = g * (yk + hd * Dsk_l[e * DSZ + t]);
                if (k == 0) yacc_s[t] = yk;
                else        h_s[t] = hd + yacc_s[t] + yk;
            }
            __syncthreads();
        }
    }

    // ---- q = h @ Wq + bq -> yacc_s (stays in LDS) ----
    {
        const int chunk = t >> 7;        // 0..7, dd-chunk of 64
        const int dquad = t & 127;
        const int dd0 = chunk * 64;
        f32x4 acc4 = {0.f, 0.f, 0.f, 0.f};
        #pragma unroll 8
        for (int i = 0; i < 64; ++i)
            acc4 += *(const f32x4*)(Wq + (size_t)(dd0 + i) * DSZ + dquad * 4) * h_s[dd0 + i];
        part4[chunk * 128 + dquad] = acc4;
    }
    __syncthreads();
    if (t < DSZ) {
        float qv = bq[t];
        #pragma unroll
        for (int c = 0; c < 8; ++c) qv += part[c * 512 + t];
        yacc_s[t] = qv;
    }
    __syncthreads();

    // ---- logits: wave w streams rows w*64 .. w*64+63 of node_emb[b] ----
    {
        const f32x4 q0 = ((const f32x4*)yacc_s)[lane];
        const f32x4 q1 = ((const f32x4*)yacc_s)[lane + 64];
        const float scale = 0.04419417382415922f;  // 1/sqrt(512)
        const int n0 = wave * 64;
        for (int i = 0; i < 64; i += 2) {
            const f32x4* r0 = (const f32x4*)(node_emb + ((size_t)b * NSZ + n0 + i) * DSZ);
            const f32x4* r1 = (const f32x4*)(node_emb + ((size_t)b * NSZ + n0 + i + 1) * DSZ);
            const f32x4 a0 = __builtin_nontemporal_load(r0 + lane);
            const f32x4 a1 = __builtin_nontemporal_load(r0 + lane + 64);
            const f32x4 c0 = __builtin_nontemporal_load(r1 + lane);
            const f32x4 c1 = __builtin_nontemporal_load(r1 + lane + 64);
            float d0 = a0.x*q0.x + a0.y*q0.y + a0.z*q0.z + a0.w*q0.w
                     + a1.x*q1.x + a1.y*q1.y + a1.z*q1.z + a1.w*q1.w;
            float d1 = c0.x*q0.x + c0.y*q0.y + c0.z*q0.z + c0.w*q0.w
                     + c1.x*q1.x + c1.y*q1.y + c1.z*q1.z + c1.w*q1.w;
            #pragma unroll
            for (int off = 32; off; off >>= 1) {
                d0 += __shfl_down(d0, off, 64);
                d1 += __shfl_down(d1, off, 64);
            }
            if (lane == 0) {
                out_logits[b * NSZ + n0 + i]     = d0 * scale;
                out_logits[b * NSZ + n0 + i + 1] = d1 * scale;
            }
        }
    }
}

// ---------------- lb_loss finisher ----------------
__global__ void loss_kernel(const float* __restrict__ acc, float* __restrict__ out)
{
    if (threadIdx.x == 0) {
        float lb = 0.f;
        for (int l = 0; l < LNUM; ++l)
            for (int e = 0; e < ENUM; ++e) {
                const float mp = acc[(l * 2 + 0) * ENUM + e] * (1.0f / BSZ);
                const float ms = acc[(l * 2 + 1) * ENUM + e] * (1.0f / BSZ);
                lb += (float)ENUM * mp * ms;
            }
        out[0] = lb;
    }
}

extern "C" void kernel_launch(void* const* d_in, const int* in_sizes, int n_in,
                              void* d_out, int out_size, void* d_ws, size_t ws_size,
                              hipStream_t stream) {
    const float* token    = (const float*)d_in[0];  // B,1,D
    const float* node_emb = (const float*)d_in[1];  // B,N,D
    const float* states   = (const float*)d_in[2];  // L,E,B,DS
    const float* Wg       = (const float*)d_in[3];  // L,D,E
    const float* bg       = (const float*)d_in[4];  // L,E
    const float* A        = (const float*)d_in[5];  // L,E,DS
    const float* Bin      = (const float*)d_in[6];  // L,E,D,DS
    const float* Cout     = (const float*)d_in[7];  // L,E,DS,D
    const float* Dsk      = (const float*)d_in[8];  // L,E,D
    const float* Wq       = (const float*)d_in[9];  // D,D
    const float* bq       = (const float*)d_in[10]; // D

    float* out_logits = (float*)d_out;                                  // B*N
    float* out_states = out_logits + (size_t)BSZ * NSZ;                 // L*E*B*DS
    float* out_loss   = out_states + (size_t)LNUM * ENUM * BSZ * SSZ;   // 1

    float* ws_acc = (float*)d_ws;   // 48 floats

    (void)hipMemsetAsync(ws_acc, 0, sizeof(float) * LNUM * 16, stream);

    mega_kernel<<<BSZ, 1024, 0, stream>>>(
        token, node_emb, states, Wg, bg, A, Bin, Cout, Dsk, Wq, bq,
        out_logits, out_states, ws_acc);

    loss_kernel<<<1, 64, 0, stream>>>(ws_acc, out_loss);
}